// Round 11
// baseline (1073.154 us; speedup 1.0000x reference)
//
#include <hip/hip_runtime.h>

typedef __attribute__((ext_vector_type(4))) float f32x4;
typedef _Float16 f16;
typedef __attribute__((ext_vector_type(2))) _Float16 f16x2;
typedef __attribute__((ext_vector_type(8))) _Float16 f16x8;

#define T_LEN 2048
#define B_SZ 256
#define FEATN 128
#define H 50
#define H3 150
#define XW_STRIDE 160

__device__ __forceinline__ float rcpf(float x) { return __builtin_amdgcn_rcpf(x); }

__device__ __forceinline__ float dot2f(f16x2 a, f16x2 b, float c) {
#if __has_builtin(__builtin_amdgcn_fdot2)
  return __builtin_amdgcn_fdot2(a, b, c, false);
#else
  return fmaf((float)a[1], (float)b[1], fmaf((float)a[0], (float)b[0], c));
#endif
}

// ---------------- Phase 1: xw[m][k] = x[m][:] @ W[:][k]  (f16 out, no bias) ----
__global__ __launch_bounds__(256) void xw_gemm(const float* __restrict__ x,
                                               const float* __restrict__ W,
                                               f16* __restrict__ xw) {
  __shared__ f16 Wt[160 * 136];  // [n][k], row stride 136 halves
  const int tid = threadIdx.x;
  for (int idx = tid; idx < FEATN * H3; idx += 256) {
    int f = idx / H3;
    int n = idx - f * H3;
    Wt[n * 136 + f] = (f16)W[idx];
  }
  for (int idx = tid; idx < 10 * FEATN; idx += 256) {  // zero-pad n = 150..159
    int n = H3 + (idx >> 7);
    int f = idx & 127;
    Wt[n * 136 + f] = (f16)0.f;
  }
  __syncthreads();

  const int wid = tid >> 6;
  const int lane = tid & 63;
  const int l15 = lane & 15;
  const int g = lane >> 4;
  const long row0 = (long)blockIdx.x * 128 + wid * 32;

  f16x8 a[2][4];
#pragma unroll
  for (int sub = 0; sub < 2; ++sub) {
    const float* xp = x + (row0 + sub * 16 + l15) * FEATN + g * 8;
#pragma unroll
    for (int kk = 0; kk < 4; ++kk) {
      f32x4 p0 = *(const f32x4*)(xp + kk * 32);
      f32x4 p1 = *(const f32x4*)(xp + kk * 32 + 4);
      f16x8 v;
      v[0] = (f16)p0[0]; v[1] = (f16)p0[1]; v[2] = (f16)p0[2]; v[3] = (f16)p0[3];
      v[4] = (f16)p1[0]; v[5] = (f16)p1[1]; v[6] = (f16)p1[2]; v[7] = (f16)p1[3];
      a[sub][kk] = v;
    }
  }

  for (int nt = 0; nt < 10; ++nt) {
    const f16* bp = &Wt[(nt * 16 + l15) * 136 + g * 8];
    f16x8 bf0 = *(const f16x8*)(bp);
    f16x8 bf1 = *(const f16x8*)(bp + 32);
    f16x8 bf2 = *(const f16x8*)(bp + 64);
    f16x8 bf3 = *(const f16x8*)(bp + 96);
    f32x4 acc0 = {0.f, 0.f, 0.f, 0.f};
    f32x4 acc1 = {0.f, 0.f, 0.f, 0.f};
    acc0 = __builtin_amdgcn_mfma_f32_16x16x32_f16(a[0][0], bf0, acc0, 0, 0, 0);
    acc0 = __builtin_amdgcn_mfma_f32_16x16x32_f16(a[0][1], bf1, acc0, 0, 0, 0);
    acc0 = __builtin_amdgcn_mfma_f32_16x16x32_f16(a[0][2], bf2, acc0, 0, 0, 0);
    acc0 = __builtin_amdgcn_mfma_f32_16x16x32_f16(a[0][3], bf3, acc0, 0, 0, 0);
    acc1 = __builtin_amdgcn_mfma_f32_16x16x32_f16(a[1][0], bf0, acc1, 0, 0, 0);
    acc1 = __builtin_amdgcn_mfma_f32_16x16x32_f16(a[1][1], bf1, acc1, 0, 0, 0);
    acc1 = __builtin_amdgcn_mfma_f32_16x16x32_f16(a[1][2], bf2, acc1, 0, 0, 0);
    acc1 = __builtin_amdgcn_mfma_f32_16x16x32_f16(a[1][3], bf3, acc1, 0, 0, 0);
    int col = nt * 16 + l15;
    if (col < H3) {
#pragma unroll
      for (int r = 0; r < 4; ++r) {
        long rowA = row0 + g * 4 + r;
        xw[rowA * XW_STRIDE + col] = (f16)acc0[r];
        xw[(rowA + 16) * XW_STRIDE + col] = (f16)acc1[r];
      }
    }
  }
}

// ---------------- Phase 2: ILP-2 — two independent rows per wave -------------
// Block b handles batch rows b and b+128. Half-step-offset software pipeline:
// each row's LDS write->read turnaround + transcendental tail is covered by
// the OTHER row's ~200cy of independent dot issue. At 1 wave/SIMD this is the
// only latency-hiding available (no co-resident waves).
__global__ __launch_bounds__(64, 1) void gru_head64(const f16* __restrict__ xw,
                                                    const float* __restrict__ U,
                                                    const float* __restrict__ bias,
                                                    const float* __restrict__ W2,
                                                    const float* __restrict__ b2,
                                                    float* __restrict__ out) {
  __shared__ __align__(16) f16 hA[64];
  __shared__ __align__(16) f16 hB[64];
  __shared__ float finA[52], finB[52];
  __shared__ float redA[8], redB[8];
  const int l = threadIdx.x;
  const int b = blockIdx.x;  // 0..127
  const int lc = l < H ? l : H - 1;
  const bool act = l < H;
  const long baseA = (long)b * T_LEN * XW_STRIDE;
  const long baseB = (long)(b + 128) * T_LEN * XW_STRIDE;

  // U columns (z,r,h) for this lane, packed f16 pairs: 75 VGPRs, shared by rows.
  f16x2 uz2[25], ur2[25], uh2[25];
#pragma unroll
  for (int c = 0; c < 25; ++c) {
    uz2[c][0] = (f16)U[(2 * c) * H3 + lc];
    uz2[c][1] = (f16)U[(2 * c + 1) * H3 + lc];
    ur2[c][0] = (f16)U[(2 * c) * H3 + H + lc];
    ur2[c][1] = (f16)U[(2 * c + 1) * H3 + H + lc];
    uh2[c][0] = (f16)U[(2 * c) * H3 + 2 * H + lc];
    uh2[c][1] = (f16)U[(2 * c + 1) * H3 + 2 * H + lc];
  }
  const float bz = bias[lc] + bias[H3 + lc];
  const float br = bias[H + lc] + bias[H3 + H + lc];
  const float b0h = bias[2 * H + lc];
  const float b1h = bias[H3 + 2 * H + lc];

  float hrA = 0.f, hrB = 0.f;
  hA[l] = (f16)0.f;
  hB[l] = (f16)0.f;

  const f16* qA = xw + baseA + lc;
  const f16* qB = xw + baseB + lc;

  f16 pzA[4], prA[4], phA[4], pzB[4], prB[4], phB[4];
#pragma unroll
  for (int p = 0; p < 4; ++p) {
    pzA[p] = qA[p * XW_STRIDE];
    prA[p] = qA[p * XW_STRIDE + H];
    phA[p] = qA[p * XW_STRIDE + 2 * H];
    pzB[p] = qB[p * XW_STRIDE];
    prB[p] = qB[p * XW_STRIDE + H];
    phB[p] = qB[p * XW_STRIDE + 2 * H];
  }

  const f16x8* hp8A = (const f16x8*)hA;
  const f16x8* hp8B = (const f16x8*)hB;

  f16x2 hvA[25], hvB[25];

#define READH(HV, HP, HS)                                                     \
  {                                                                           \
    f16x8 w0 = (HP)[0], w1 = (HP)[1], w2 = (HP)[2];                           \
    f16x8 w3 = (HP)[3], w4 = (HP)[4], w5 = (HP)[5];                           \
    f16x2 w6 = *(const f16x2*)((HS) + 48);                                    \
    HV[0] = __builtin_shufflevector(w0, w0, 0, 1);                            \
    HV[1] = __builtin_shufflevector(w0, w0, 2, 3);                            \
    HV[2] = __builtin_shufflevector(w0, w0, 4, 5);                            \
    HV[3] = __builtin_shufflevector(w0, w0, 6, 7);                            \
    HV[4] = __builtin_shufflevector(w1, w1, 0, 1);                            \
    HV[5] = __builtin_shufflevector(w1, w1, 2, 3);                            \
    HV[6] = __builtin_shufflevector(w1, w1, 4, 5);                            \
    HV[7] = __builtin_shufflevector(w1, w1, 6, 7);                            \
    HV[8] = __builtin_shufflevector(w2, w2, 0, 1);                            \
    HV[9] = __builtin_shufflevector(w2, w2, 2, 3);                            \
    HV[10] = __builtin_shufflevector(w2, w2, 4, 5);                           \
    HV[11] = __builtin_shufflevector(w2, w2, 6, 7);                           \
    HV[12] = __builtin_shufflevector(w3, w3, 0, 1);                           \
    HV[13] = __builtin_shufflevector(w3, w3, 2, 3);                           \
    HV[14] = __builtin_shufflevector(w3, w3, 4, 5);                           \
    HV[15] = __builtin_shufflevector(w3, w3, 6, 7);                           \
    HV[16] = __builtin_shufflevector(w4, w4, 0, 1);                           \
    HV[17] = __builtin_shufflevector(w4, w4, 2, 3);                           \
    HV[18] = __builtin_shufflevector(w4, w4, 4, 5);                           \
    HV[19] = __builtin_shufflevector(w4, w4, 6, 7);                           \
    HV[20] = __builtin_shufflevector(w5, w5, 0, 1);                           \
    HV[21] = __builtin_shufflevector(w5, w5, 2, 3);                           \
    HV[22] = __builtin_shufflevector(w5, w5, 4, 5);                           \
    HV[23] = __builtin_shufflevector(w5, w5, 6, 7);                           \
    HV[24] = w6;                                                              \
  }

  READH(hvA, hp8A, hA)
  READH(hvB, hp8B, hB)

  // One row's half-step: dots -> tail -> write h(t+1) -> read h(t+1).
#define HALF(HV, HP, HS, HR, PZ, PR, PH, Q, P, PF)                            \
    {                                                                         \
      float sz0 = bz, sr0 = br, sh0 = b1h;                                    \
      float sz1 = 0.f, sr1 = 0.f, sh1 = 0.f;                                  \
      _Pragma("unroll")                                                       \
      for (int p = 0; p < 25; ++p) {                                          \
        if (p & 1) {                                                          \
          sz1 = dot2f(HV[p], uz2[p], sz1);                                    \
          sr1 = dot2f(HV[p], ur2[p], sr1);                                    \
          sh1 = dot2f(HV[p], uh2[p], sh1);                                    \
        } else {                                                              \
          sz0 = dot2f(HV[p], uz2[p], sz0);                                    \
          sr0 = dot2f(HV[p], ur2[p], sr0);                                    \
          sh0 = dot2f(HV[p], uh2[p], sh0);                                    \
        }                                                                     \
      }                                                                       \
      float xzf = (float)PZ[P];                                               \
      float xrf = (float)PR[P];                                               \
      float xhf = (float)PH[P];                                               \
      if (PF) {                                                               \
        PZ[P] = Q[(P + 4) * XW_STRIDE];                                       \
        PR[P] = Q[(P + 4) * XW_STRIDE + H];                                   \
        PH[P] = Q[(P + 4) * XW_STRIDE + 2 * H];                               \
      }                                                                       \
      float ar = (sr0 + sr1) + xrf;                                           \
      float er = __expf(-ar);                                                 \
      float az = (sz0 + sz1) + xzf;                                           \
      float ez = __expf(-az);                                                 \
      float rr = rcpf(1.f + er);                                              \
      float zz = rcpf(1.f + ez);                                              \
      float ah = fmaf(rr, sh0 + sh1, xhf + b0h);                              \
      float eh = __expf(-2.f * ah);                                           \
      float th = fmaf(2.f, rcpf(1.f + eh), -1.f);                             \
      HR = fmaf(zz, HR - th, th);                                             \
      HS[l] = (f16)HR;                                                        \
      READH(HV, HP, HS)                                                       \
    }

#define STEPPAIR(P, PF)                                                       \
    HALF(hvA, hp8A, hA, hrA, pzA, prA, phA, qA, P, PF)                        \
    HALF(hvB, hp8B, hB, hrB, pzB, prB, phB, qB, P, PF)

  for (int t0 = 0; t0 < T_LEN - 4; t0 += 4) {
    STEPPAIR(0, 1) STEPPAIR(1, 1) STEPPAIR(2, 1) STEPPAIR(3, 1)
    qA += 4 * XW_STRIDE;
    qB += 4 * XW_STRIDE;
  }
  // final group: no prefetch (avoids OOB reads past the workspace)
  STEPPAIR(0, 0) STEPPAIR(1, 0) STEPPAIR(2, 0) STEPPAIR(3, 0)
#undef STEPPAIR
#undef HALF
#undef READH

  // LeakyReLU(0.3) + dense(50->8) + softmax for both rows (single wave)
  if (act) {
    finA[l] = hrA >= 0.f ? hrA : 0.3f * hrA;
    finB[l] = hrB >= 0.f ? hrB : 0.3f * hrB;
  }
  if (l < 8) {
    float accA = b2[l], accB = b2[l];
#pragma unroll
    for (int j = 0; j < H; ++j) {
      accA = fmaf(finA[j], W2[j * 8 + l], accA);
      accB = fmaf(finB[j], W2[j * 8 + l], accB);
    }
    redA[l] = accA;
    redB[l] = accB;
  }
  if (l < 8) {
    float mA = redA[0], mB = redB[0];
#pragma unroll
    for (int i = 1; i < 8; ++i) {
      mA = fmaxf(mA, redA[i]);
      mB = fmaxf(mB, redB[i]);
    }
    float sA = 0.f, sB = 0.f;
#pragma unroll
    for (int i = 0; i < 8; ++i) {
      sA += __expf(redA[i] - mA);
      sB += __expf(redB[i] - mB);
    }
    out[b * 8 + l] = __expf(redA[l] - mA) / sA;
    out[(b + 128) * 8 + l] = __expf(redB[l] - mB) / sB;
  }
}

extern "C" void kernel_launch(void* const* d_in, const int* in_sizes, int n_in,
                              void* d_out, int out_size, void* d_ws, size_t ws_size,
                              hipStream_t stream) {
  const float* x = (const float*)d_in[0];
  const float* W = (const float*)d_in[1];
  const float* U = (const float*)d_in[2];
  const float* bias = (const float*)d_in[3];
  const float* W2 = (const float*)d_in[4];
  const float* b2 = (const float*)d_in[5];
  float* out = (float*)d_out;
  f16* xw = (f16*)d_ws;  // [B*T][160] f16, ~168 MB

  xw_gemm<<<4096, 256, 0, stream>>>(x, W, xw);
  gru_head64<<<128, 64, 0, stream>>>(xw, U, bias, W2, b2, out);
}